// Round 12
// baseline (567.101 us; speedup 1.0000x reference)
//
#include <hip/hip_runtime.h>
#include <hip/hip_bf16.h>

#define N_NODES 50000
#define N_EDGES 800000
#define IN_C 128
#define HC 128
#define HEADS 8
#define NEG_SLOPE 0.2f
#define LN_EPS 1e-5f

#define LDH 136                 // per-wave h-tile row stride (128 + 8 pad)
#define ELL_CAP 64              // slots per node; max degree ~40 (Poisson 16)
#define GRID 1024               // exactly 4 blocks/CU co-resident (see launch_bounds math)
#define NTHREADS (GRID * 256)   // 262144
#define GEMM_WAVES 3125         // 3125 * 16 nodes = 50000

typedef __hip_bfloat16 bf16;
typedef __attribute__((ext_vector_type(8))) short short8;
typedef __attribute__((ext_vector_type(4))) float f32x4;

__device__ __forceinline__ float b2f(bf16 v) { return __bfloat162float(v); }

// float -> bf16 bits, round-to-nearest-even
__device__ __forceinline__ unsigned short f2bf(float f) {
    unsigned u = __float_as_uint(f);
    return (unsigned short)((u + 0x7fffu + ((u >> 16) & 1u)) >> 16);
}
__device__ __forceinline__ float bf2f(unsigned s) {
    return __uint_as_float(s << 16);
}
__device__ __forceinline__ short8 pack8(float4 u, float4 v) {
    short8 r;
    r[0] = (short)f2bf(u.x); r[1] = (short)f2bf(u.y);
    r[2] = (short)f2bf(u.z); r[3] = (short)f2bf(u.w);
    r[4] = (short)f2bf(v.x); r[5] = (short)f2bf(v.y);
    r[6] = (short)f2bf(v.z); r[7] = (short)f2bf(v.w);
    return r;
}

// Software grid barrier: 1024 co-resident blocks, monotonic counter per phase.
// Agent-scope atomics + fences (the cg::grid_group mechanism, minus the API).
__device__ __forceinline__ void grid_barrier(unsigned* bar) {
    __syncthreads();
    if (threadIdx.x == 0) {
        __threadfence();                       // release: wb dirty lines
        __hip_atomic_fetch_add(bar, 1u, __ATOMIC_ACQ_REL, __HIP_MEMORY_SCOPE_AGENT);
        while (__hip_atomic_load(bar, __ATOMIC_ACQUIRE, __HIP_MEMORY_SCOPE_AGENT) < GRID)
            __builtin_amdgcn_s_sleep(8);
    }
    __syncthreads();
    __threadfence();                           // acquire: invalidate stale lines
}

// ---------------------------------------------------------------------------
// Persistent mega-kernel: P0 prep -> P1 (GEMM || ELL-fill) -> P2 gather.
// Replaces 3 dispatches (+2 boundaries ~25-35 us each) with 2 ~3 us barriers.
// ---------------------------------------------------------------------------
__global__ __launch_bounds__(256, 4) void mega(
    const float* __restrict__ x, const float* __restrict__ W,
    const float* __restrict__ att_src, const float* __restrict__ att_dst,
    const int* __restrict__ ei, const float* __restrict__ edge_attr,
    const float* __restrict__ bvec,
    const float* __restrict__ gamma, const float* __restrict__ beta,
    const float* __restrict__ att_edge, const float* __restrict__ lin_w,
    const float* __restrict__ lin_b,
    unsigned short* Wt, int* cnt, unsigned int* ellp, unsigned* bar,
    unsigned short* h_ws, float* a_src, float* a_dst,
    float* __restrict__ out)
{
    __shared__ short sH[4][16 * LDH];          // 17408 B; GEMM waves only
    const int bid = blockIdx.x;
    const int t   = threadIdx.x;
    const int wv  = t >> 6;
    const int l   = t & 63;
    const int id  = bid * 256 + t;

    // ---------------- P0: Wt build (bf16, transposed) + cnt zero ----------
    if (id < 16384) {                          // W is 128x128 fp32, coalesced
        int k = id >> 7, n = id & 127;
        Wt[n * 128 + k] = f2bf(W[id]);
    }
    if (id < N_NODES) cnt[id] = 0;
    grid_barrier(&bar[0]);

    // ---------------- P1: GEMM (waves < 3125) || ELL fill (all) -----------
    const int gw = bid * 4 + wv;
    if (gw < GEMM_WAVES) {
        const int n0   = gw * 16;
        const int mrow = l & 15;
        const int quad = l >> 4;

        short8 afrag[4];
        const float* xr = x + (size_t)(n0 + mrow) * IN_C + quad * 8;
#pragma unroll
        for (int ko = 0; ko < 4; ++ko) {
            float4 u = *reinterpret_cast<const float4*>(xr + ko * 32);
            float4 v = *reinterpret_cast<const float4*>(xr + ko * 32 + 4);
            afrag[ko] = pack8(u, v);
        }

        f32x4 acc[8];
#pragma unroll
        for (int nt = 0; nt < 8; ++nt) acc[nt] = (f32x4)0.f;
#pragma unroll
        for (int nt = 0; nt < 8; ++nt) {
            const unsigned short* wr = Wt + (nt * 16 + mrow) * 128 + quad * 8;
#pragma unroll
            for (int ko = 0; ko < 4; ++ko) {
                short8 bfr = *reinterpret_cast<const short8*>(wr + ko * 32);
                acc[nt] = __builtin_amdgcn_mfma_f32_16x16x32_bf16(
                    afrag[ko], bfr, acc[nt], 0, 0, 0);
            }
        }

        // C -> per-wave LDS tile. C/D layout: col = lane&15, row = quad*4+r.
#pragma unroll
        for (int nt = 0; nt < 8; ++nt)
#pragma unroll
            for (int r = 0; r < 4; ++r)
                sH[wv][(quad * 4 + r) * LDH + nt * 16 + mrow] =
                    (short)f2bf(acc[nt][r]);
        // within-wave LDS write->read: lockstep + compiler lgkmcnt, no barrier

        // h store: 16 rows x 128 cols bf16, 16B per lane per iter
#pragma unroll
        for (int i = 0; i < 4; ++i) {
            int row = i * 4 + (l >> 4);
            int col = (l & 15) * 8;
            short8 hv = *reinterpret_cast<const short8*>(&sH[wv][row * LDH + col]);
            *reinterpret_cast<short8*>(h_ws + (size_t)(n0 + row) * HC + col) = hv;
        }

        // a_src/a_dst: 128 (node,head) pairs per wave, 2 per lane
#pragma unroll
        for (int pp = 0; pp < 2; ++pp) {
            int p  = l + pp * 64;
            int m  = p >> 3;
            int hd = p & 7;
            float ssum = 0.f, dsum = 0.f;
#pragma unroll
            for (int c = 0; c < 16; ++c) {
                float hv = bf2f((unsigned short)sH[wv][m * LDH + hd * 16 + c]);
                ssum = fmaf(hv, att_src[hd * 16 + c], ssum);
                dsum = fmaf(hv, att_dst[hd * 16 + c], dsum);
            }
            a_src[(n0 + m) * HEADS + hd] = ssum;
            a_dst[(n0 + m) * HEADS + hd] = dsum;
        }
    }

    // ELL fill, grid-strided over ALL blocks. Entry: {src:16 | ea_bf16:16}.
    for (int e = id; e < N_EDGES; e += NTHREADS) {
        int d   = ei[N_EDGES + e];
        int pos = atomicAdd(&cnt[d], 1);
        if (pos < ELL_CAP)
            ellp[(d << 6) + pos] =
                (((unsigned)ei[e]) << 16) | (unsigned)f2bf(edge_attr[e]);
    }
    grid_barrier(&bar[1]);

    // ---------------- P2: persistent gather ----------------
    const int hh = l >> 3;                     // head
    const int jj = l & 7;                      // edge-in-chunk

    float ae0 = att_edge[2 * l], ae1 = att_edge[2 * l + 1];
    float p = ae0 * lin_w[2 * l] + ae1 * lin_w[2 * l + 1];
    float q = ae0 * lin_b[2 * l] + ae1 * lin_b[2 * l + 1];
#pragma unroll
    for (int off = 1; off <= 4; off <<= 1) {
        p += __shfl_xor(p, off, 64);
        q += __shfl_xor(q, off, 64);
    }
    const float2 bv = *reinterpret_cast<const float2*>(bvec + 2 * l);
    const float2 gv = *reinterpret_cast<const float2*>(gamma + 2 * l);
    const float2 be = *reinterpret_cast<const float2*>(beta + 2 * l);

    const __hip_bfloat162* h2 = reinterpret_cast<const __hip_bfloat162*>(h_ws);

    for (int grp = bid; grp < N_NODES / 4; grp += GRID) {
        const int n    = grp * 4 + wv;
        const float ad   = a_dst[n * HEADS + hh];
        const int   beg  = n << 6;
        const int   cn   = min(cnt[n], ELL_CAP);
        const int   full = cn & ~7;

        float zp = 0.f, acc0 = 0.f, acc1 = 0.f;

        for (int bs = 0; bs < full; bs += 8) {
            unsigned ce = ellp[beg + bs + jj];
            const int   sl = ce >> 16;
            const float ea = bf2f(ce & 0xffffu);
            float lg = a_src[sl * HEADS + hh] + ad + ea * p + q;
            lg = lg > 0.f ? lg : NEG_SLOPE * lg;
            const float ev = __expf(lg);
            zp += ev;
            const int pk = (sl << 16) | (int)f2bf(ev);   // {src:16 | ev_bf16:16}

            // broadcast lane (l&56)|j within each 8-lane head group
#define GSTEP(OFF)                                                        \
            {                                                             \
                int pj = __builtin_amdgcn_ds_swizzle(pk, OFF);            \
                int sj = ((unsigned)pj) >> 16;                            \
                float evj = bf2f((unsigned)pj & 0xffffu);                 \
                __hip_bfloat162 hv = h2[(size_t)sj * 64 + l];             \
                acc0 += evj * b2f(hv.x);                                  \
                acc1 += evj * b2f(hv.y);                                  \
            }
            GSTEP(24)  GSTEP(56)  GSTEP(88)  GSTEP(120)
            GSTEP(152) GSTEP(184) GSTEP(216) GSTEP(248)
#undef GSTEP
        }

        const int rem = cn - full;
        if (rem > 0) {
            int sl = 0; float ev = 0.f;
            if (jj < rem) {
                unsigned ce = ellp[beg + full + jj];
                sl = ce >> 16;
                float ea = bf2f(ce & 0xffffu);
                float lg = a_src[sl * HEADS + hh] + ad + ea * p + q;
                lg = lg > 0.f ? lg : NEG_SLOPE * lg;
                ev = __expf(lg);
            }
            zp += ev;
            const int gbase = l & 56;
            for (int j = 0; j < rem; ++j) {
                float evj = __shfl(ev, gbase | j, 64);
                int   sj  = __shfl(sl, gbase | j, 64);
                __hip_bfloat162 hv = h2[(size_t)sj * 64 + l];
                acc0 += evj * b2f(hv.x);
                acc1 += evj * b2f(hv.y);
            }
        }

        // softmax denom across the 8 lanes of this head group
        float z = zp;
        z += __shfl_xor(z, 1, 64);
        z += __shfl_xor(z, 2, 64);
        z += __shfl_xor(z, 4, 64);
        const float rz = 1.f / (z + 1e-16f);
        acc0 *= rz;
        acc1 *= rz;

        // epilogue: +bias +residual, LayerNorm over 128 ch, ELU, store
        const size_t idx = (size_t)n * HC + 2 * l;
        const float2 xv = *reinterpret_cast<const float2*>(x + idx);
        float v0 = acc0 + xv.x + bv.x;
        float v1 = acc1 + xv.y + bv.y;
        float s1 = v0 + v1, s2 = v0 * v0 + v1 * v1;
#pragma unroll
        for (int off = 32; off >= 1; off >>= 1) {
            s1 += __shfl_xor(s1, off, 64);
            s2 += __shfl_xor(s2, off, 64);
        }
        const float mean = s1 * (1.f / HC);
        const float var  = s2 * (1.f / HC) - mean * mean;
        const float inv  = rsqrtf(var + LN_EPS);
        float y0 = (v0 - mean) * inv * gv.x + be.x;
        float y1 = (v1 - mean) * inv * gv.y + be.y;
        y0 = y0 > 0.f ? y0 : expm1f(y0);
        y1 = y1 > 0.f ? y1 : expm1f(y1);
        *reinterpret_cast<float2*>(out + idx) = make_float2(y0, y1);
    }
}

// ---------------------------------------------------------------------------
extern "C" void kernel_launch(void* const* d_in, const int* in_sizes, int n_in,
                              void* d_out, int out_size, void* d_ws, size_t ws_size,
                              hipStream_t stream)
{
    const float* x         = (const float*)d_in[0];
    const int*   ei        = (const int*)d_in[1];
    const float* edge_attr = (const float*)d_in[2];
    const float* W         = (const float*)d_in[3];
    const float* b         = (const float*)d_in[4];
    const float* att_src   = (const float*)d_in[5];
    const float* att_dst   = (const float*)d_in[6];
    const float* att_edge  = (const float*)d_in[7];
    const float* lin_w     = (const float*)d_in[8];
    const float* lin_b     = (const float*)d_in[9];
    const float* gamma     = (const float*)d_in[10];
    const float* beta      = (const float*)d_in[11];

    char* ws = (char*)d_ws;
    unsigned short* h = (unsigned short*)ws;
    ws += (size_t)N_NODES * HC * sizeof(unsigned short);                       // 12.8 MB
    float* a_src = (float*)ws; ws += (size_t)N_NODES * HEADS * sizeof(float);  //  1.6 MB
    float* a_dst = (float*)ws; ws += (size_t)N_NODES * HEADS * sizeof(float);  //  1.6 MB
    int*   cnt   = (int*)ws;   ws += (size_t)N_NODES * sizeof(int);            //  0.2 MB
    unsigned short* Wt = (unsigned short*)ws;
    ws += (size_t)128 * 128 * sizeof(unsigned short);                          //  32 KB
    unsigned* bar = (unsigned*)ws; ws += 64 * sizeof(unsigned);                // barrier ctrs
    unsigned int* ellp = (unsigned int*)ws;
    ws += (size_t)N_NODES * ELL_CAP * sizeof(unsigned int);                    // 12.8 MB

    hipMemsetAsync(bar, 0, 64 * sizeof(unsigned), stream);

    mega<<<GRID, 256, 0, stream>>>(
        x, W, att_src, att_dst, ei, edge_attr, b, gamma, beta,
        att_edge, lin_w, lin_b,
        Wt, cnt, ellp, bar, h, a_src, a_dst, (float*)d_out);
}

// Round 13
// 192.896 us; speedup vs baseline: 2.9399x; 2.9399x over previous
//
#include <hip/hip_runtime.h>
#include <hip/hip_bf16.h>

#define N_NODES 50000
#define N_EDGES 800000
#define IN_C 128
#define HC 128
#define HEADS 8
#define NEG_SLOPE 0.2f
#define LN_EPS 1e-5f

#define LDH 136                 // per-wave h-tile row stride (128 + 8 pad)
#define ELL_CAP 64              // slots per node; max degree ~40 (Poisson 16)
#define GEMM_BLOCKS 782         // ceil(3125 waves / 4)
#define FILL_BLOCKS 782         // 782*256 threads * 4 edges >= 800000
#define FUSED_BLOCKS (GEMM_BLOCKS + FILL_BLOCKS)   // 1564: all co-resident

typedef __hip_bfloat16 bf16;
typedef __attribute__((ext_vector_type(8))) short short8;
typedef __attribute__((ext_vector_type(4))) float f32x4;

__device__ __forceinline__ float b2f(bf16 v) { return __bfloat162float(v); }

// float -> bf16 bits, round-to-nearest-even
__device__ __forceinline__ unsigned short f2bf(float f) {
    unsigned u = __float_as_uint(f);
    return (unsigned short)((u + 0x7fffu + ((u >> 16) & 1u)) >> 16);
}
__device__ __forceinline__ float bf2f(unsigned s) {
    return __uint_as_float(s << 16);
}
__device__ __forceinline__ short8 pack8(float4 u, float4 v) {
    short8 r;
    r[0] = (short)f2bf(u.x); r[1] = (short)f2bf(u.y);
    r[2] = (short)f2bf(u.z); r[3] = (short)f2bf(u.w);
    r[4] = (short)f2bf(v.x); r[5] = (short)f2bf(v.y);
    r[6] = (short)f2bf(v.z); r[7] = (short)f2bf(v.w);
    return r;
}

// ---------------------------------------------------------------------------
// prep: W (fp32,[k][n]) -> Wt (bf16,[n][k]) AND zero cnt (replaces memset).
// ---------------------------------------------------------------------------
__global__ __launch_bounds__(256) void prep(
    const float* __restrict__ W, unsigned short* __restrict__ Wt,
    int* __restrict__ cnt)
{
    int id = blockIdx.x * 256 + threadIdx.x;   // 64 blocks * 256 = 16384
    int k = id >> 7, n = id & 127;
    Wt[n * 128 + k] = f2bf(W[id]);
#pragma unroll
    for (int i = 0; i < 4; ++i) {
        int j = id + i * 16384;
        if (j < N_NODES) cnt[j] = 0;
    }
}

// ---------------------------------------------------------------------------
// fused: heterogeneous blocks (interleaved even/odd for even CU spread).
//   bid even -> GEMM block (782): streaming MFMA h = x@W + a_src/a_dst.
//   bid odd  -> ELL-fill block (782): 4 consecutive edges/thread ->
//               int4/float4 loads + 4 INDEPENDENT atomic chains in flight.
// ELL entry is 4 B packed {src:16 | ea_bf16:16}.
// ---------------------------------------------------------------------------
__global__ __launch_bounds__(256) void fused(
    const float* __restrict__ x, const unsigned short* __restrict__ Wt,
    const float* __restrict__ att_src, const float* __restrict__ att_dst,
    const int* __restrict__ ei, const float* __restrict__ edge_attr,
    int* __restrict__ cnt, unsigned int* __restrict__ ellp,
    unsigned short* __restrict__ h_out,
    float* __restrict__ a_src, float* __restrict__ a_dst)
{
    __shared__ short sH[4][16 * LDH];          // 17408 B (gemm blocks only)
    const int bid = blockIdx.x;
    const int t   = threadIdx.x;

    if (bid & 1) {
        // ---------------- ELL fill: 4 edges per thread ----------------
        const int fid = bid >> 1;              // 0..781
        const int e0  = (fid * 256 + t) * 4;
        if (e0 >= N_EDGES) return;
        // 800000 % 4 == 0 and e0 multiple of 4 -> all 4 edges valid
        const int4   s4 = *reinterpret_cast<const int4*>(ei + e0);
        const int4   d4 = *reinterpret_cast<const int4*>(ei + N_EDGES + e0);
        const float4 a4 = *reinterpret_cast<const float4*>(edge_attr + e0);

        int p0 = atomicAdd(&cnt[d4.x], 1);
        int p1 = atomicAdd(&cnt[d4.y], 1);
        int p2 = atomicAdd(&cnt[d4.z], 1);
        int p3 = atomicAdd(&cnt[d4.w], 1);
        if (p0 < ELL_CAP)
            ellp[(d4.x << 6) + p0] = (((unsigned)s4.x) << 16) | (unsigned)f2bf(a4.x);
        if (p1 < ELL_CAP)
            ellp[(d4.y << 6) + p1] = (((unsigned)s4.y) << 16) | (unsigned)f2bf(a4.y);
        if (p2 < ELL_CAP)
            ellp[(d4.z << 6) + p2] = (((unsigned)s4.z) << 16) | (unsigned)f2bf(a4.z);
        if (p3 < ELL_CAP)
            ellp[(d4.w << 6) + p3] = (((unsigned)s4.w) << 16) | (unsigned)f2bf(a4.w);
        return;
    }

    // ---------------- GEMM ----------------
    const int gid = bid >> 1;                  // 0..781
    const int wv  = t >> 6;
    const int l   = t & 63;
    const int gw  = gid * 4 + wv;
    if (gw >= N_NODES / 16) return;            // 3125 active waves, no barriers

    const int n0   = gw * 16;
    const int mrow = l & 15;
    const int quad = l >> 4;

    short8 afrag[4];
    const float* xr = x + (size_t)(n0 + mrow) * IN_C + quad * 8;
#pragma unroll
    for (int ko = 0; ko < 4; ++ko) {
        float4 u = *reinterpret_cast<const float4*>(xr + ko * 32);
        float4 v = *reinterpret_cast<const float4*>(xr + ko * 32 + 4);
        afrag[ko] = pack8(u, v);
    }

    f32x4 acc[8];
#pragma unroll
    for (int nt = 0; nt < 8; ++nt) acc[nt] = (f32x4)0.f;
#pragma unroll
    for (int nt = 0; nt < 8; ++nt) {
        const unsigned short* wr = Wt + (nt * 16 + mrow) * 128 + quad * 8;
#pragma unroll
        for (int ko = 0; ko < 4; ++ko) {
            short8 bfr = *reinterpret_cast<const short8*>(wr + ko * 32);
            acc[nt] = __builtin_amdgcn_mfma_f32_16x16x32_bf16(afrag[ko], bfr, acc[nt], 0, 0, 0);
        }
    }

    // C -> per-wave LDS tile. C/D layout: col = lane&15, row = quad*4 + r.
#pragma unroll
    for (int nt = 0; nt < 8; ++nt)
#pragma unroll
        for (int r = 0; r < 4; ++r)
            sH[wv][(quad * 4 + r) * LDH + nt * 16 + mrow] = (short)f2bf(acc[nt][r]);
    // within-wave LDS write->read: lockstep + compiler lgkmcnt, no barrier

    // h store: 16 rows x 128 cols bf16, 16B per lane per iter
#pragma unroll
    for (int i = 0; i < 4; ++i) {
        int row = i * 4 + (l >> 4);
        int col = (l & 15) * 8;
        short8 hv = *reinterpret_cast<const short8*>(&sH[wv][row * LDH + col]);
        *reinterpret_cast<short8*>(h_out + (size_t)(n0 + row) * HC + col) = hv;
    }

    // a_src/a_dst: 128 (node,head) pairs per wave, 2 per lane
#pragma unroll
    for (int pp = 0; pp < 2; ++pp) {
        int p  = l + pp * 64;
        int m  = p >> 3;
        int hd = p & 7;
        float ssum = 0.f, dsum = 0.f;
#pragma unroll
        for (int c = 0; c < 16; ++c) {
            float hv = bf2f((unsigned short)sH[wv][m * LDH + hd * 16 + c]);
            ssum = fmaf(hv, att_src[hd * 16 + c], ssum);
            dsum = fmaf(hv, att_dst[hd * 16 + c], dsum);
        }
        a_src[(n0 + m) * HEADS + hd] = ssum;
        a_dst[(n0 + m) * HEADS + hd] = dsum;
    }
}

// ---------------------------------------------------------------------------
// gather: single-pass softmax, depth-2 software pipeline — next chunk's ellp
// word AND its a_src are prefetched one iteration ahead, overlapping the
// dependent-load chain (ellp -> a_src) with the current chunk's h-FMA tail.
// ---------------------------------------------------------------------------
__global__ __launch_bounds__(256) void gather_node(
    const int* __restrict__ cnt, const unsigned int* __restrict__ ellp,
    const float* __restrict__ a_src, const float* __restrict__ a_dst,
    const bf16* __restrict__ h,
    const float* __restrict__ x, const float* __restrict__ bvec,
    const float* __restrict__ gamma, const float* __restrict__ beta,
    const float* __restrict__ att_edge, const float* __restrict__ lin_w,
    const float* __restrict__ lin_b,
    float* __restrict__ out)
{
    const int wave = threadIdx.x >> 6;
    const int l    = threadIdx.x & 63;
    const int n    = blockIdx.x * 4 + wave;       // 50000 % 4 == 0
    const int hh   = l >> 3;
    const int jj   = l & 7;

    float ae0 = att_edge[2 * l], ae1 = att_edge[2 * l + 1];
    float p = ae0 * lin_w[2 * l] + ae1 * lin_w[2 * l + 1];
    float q = ae0 * lin_b[2 * l] + ae1 * lin_b[2 * l + 1];
#pragma unroll
    for (int off = 1; off <= 4; off <<= 1) {
        p += __shfl_xor(p, off, 64);
        q += __shfl_xor(q, off, 64);
    }
    const float2 bv = *reinterpret_cast<const float2*>(bvec + 2 * l);
    const float2 gv = *reinterpret_cast<const float2*>(gamma + 2 * l);
    const float2 be = *reinterpret_cast<const float2*>(beta + 2 * l);

    const float ad  = a_dst[n * HEADS + hh];
    const int   beg = n << 6;
    const int   cn  = min(cnt[n], ELL_CAP);
    const int   full = cn & ~7;

    float zp = 0.f, acc0 = 0.f, acc1 = 0.f;
    const __hip_bfloat162* h2 = reinterpret_cast<const __hip_bfloat162*>(h);

    if (full > 0) {
        // pipeline prologue: chunk 0's ell word + its a_src
        unsigned ce_c = ellp[beg + jj];
        float    as_c = a_src[(ce_c >> 16) * HEADS + hh];

        for (int bs = 0; bs < full; bs += 8) {
            const unsigned ce = ce_c;
            const float    as = as_c;
            // prefetch next chunk (ellp padded by 256B -> unconditional OK)
            ce_c = ellp[beg + bs + 8 + jj];

            const int   sl = ce >> 16;
            const float ea = bf2f(ce & 0xffffu);
            float lg = as + ad + ea * p + q;
            lg = lg > 0.f ? lg : NEG_SLOPE * lg;
            const float ev = __expf(lg);
            zp += ev;
            const int pk = (sl << 16) | (int)f2bf(ev);   // {src:16 | ev_bf16:16}

            as_c = a_src[(ce_c >> 16) * HEADS + hh];     // next chunk's a_src

            // broadcast lane (l&56)|j within each 8-lane head group
#define GSTEP(OFF)                                                        \
            {                                                             \
                int pj = __builtin_amdgcn_ds_swizzle(pk, OFF);            \
                int sj = ((unsigned)pj) >> 16;                            \
                float evj = bf2f((unsigned)pj & 0xffffu);                 \
                __hip_bfloat162 hv = h2[(size_t)sj * 64 + l];             \
                acc0 += evj * b2f(hv.x);                                  \
                acc1 += evj * b2f(hv.y);                                  \
            }
            GSTEP(24)  GSTEP(56)  GSTEP(88)  GSTEP(120)
            GSTEP(152) GSTEP(184) GSTEP(216) GSTEP(248)
#undef GSTEP
        }
    }

    const int rem = cn - full;
    if (rem > 0) {
        int sl = 0; float ev = 0.f;
        if (jj < rem) {
            unsigned ce = ellp[beg + full + jj];
            sl = ce >> 16;
            float ea = bf2f(ce & 0xffffu);
            float lg = a_src[sl * HEADS + hh] + ad + ea * p + q;
            lg = lg > 0.f ? lg : NEG_SLOPE * lg;
            ev = __expf(lg);
        }
        zp += ev;
        const int gbase = l & 56;
        for (int j = 0; j < rem; ++j) {
            float evj = __shfl(ev, gbase | j, 64);
            int   sj  = __shfl(sl, gbase | j, 64);
            __hip_bfloat162 hv = h2[(size_t)sj * 64 + l];
            acc0 += evj * b2f(hv.x);
            acc1 += evj * b2f(hv.y);
        }
    }

    // z: reduce per-lane partials across the 8 lanes of this head group
    float z = zp;
    z += __shfl_xor(z, 1, 64);
    z += __shfl_xor(z, 2, 64);
    z += __shfl_xor(z, 4, 64);
    const float rz = 1.f / (z + 1e-16f);
    acc0 *= rz;
    acc1 *= rz;

    const size_t idx = (size_t)n * HC + 2 * l;
    const float2 xv = *reinterpret_cast<const float2*>(x + idx);
    float v0 = acc0 + xv.x + bv.x;
    float v1 = acc1 + xv.y + bv.y;
    float s1 = v0 + v1, s2 = v0 * v0 + v1 * v1;
#pragma unroll
    for (int off = 32; off >= 1; off >>= 1) {
        s1 += __shfl_xor(s1, off, 64);
        s2 += __shfl_xor(s2, off, 64);
    }
    const float mean = s1 * (1.f / HC);
    const float var  = s2 * (1.f / HC) - mean * mean;
    const float inv  = rsqrtf(var + LN_EPS);
    float y0 = (v0 - mean) * inv * gv.x + be.x;
    float y1 = (v1 - mean) * inv * gv.y + be.y;
    y0 = y0 > 0.f ? y0 : expm1f(y0);
    y1 = y1 > 0.f ? y1 : expm1f(y1);
    *reinterpret_cast<float2*>(out + idx) = make_float2(y0, y1);
}

// ---------------------------------------------------------------------------
extern "C" void kernel_launch(void* const* d_in, const int* in_sizes, int n_in,
                              void* d_out, int out_size, void* d_ws, size_t ws_size,
                              hipStream_t stream)
{
    const float* x         = (const float*)d_in[0];
    const int*   ei        = (const int*)d_in[1];
    const float* edge_attr = (const float*)d_in[2];
    const float* W         = (const float*)d_in[3];
    const float* b         = (const float*)d_in[4];
    const float* att_src   = (const float*)d_in[5];
    const float* att_dst   = (const float*)d_in[6];
    const float* att_edge  = (const float*)d_in[7];
    const float* lin_w     = (const float*)d_in[8];
    const float* lin_b     = (const float*)d_in[9];
    const float* gamma     = (const float*)d_in[10];
    const float* beta      = (const float*)d_in[11];

    char* ws = (char*)d_ws;
    bf16*  h     = (bf16*)ws;  ws += (size_t)N_NODES * HC * sizeof(bf16);      // 12.8 MB
    float* a_src = (float*)ws; ws += (size_t)N_NODES * HEADS * sizeof(float);  //  1.6 MB
    float* a_dst = (float*)ws; ws += (size_t)N_NODES * HEADS * sizeof(float);  //  1.6 MB
    int*   cnt   = (int*)ws;   ws += (size_t)N_NODES * sizeof(int);            //  0.2 MB
    unsigned short* Wt = (unsigned short*)ws;
    ws += (size_t)128 * 128 * sizeof(unsigned short);                          //  32 KB
    unsigned int* ellp = (unsigned int*)ws;
    ws += (size_t)(N_NODES * ELL_CAP + 64) * sizeof(unsigned int);             // 12.8 MB + pad

    prep<<<64, 256, 0, stream>>>(W, Wt, cnt);

    fused<<<FUSED_BLOCKS, 256, 0, stream>>>(
        x, Wt, att_src, att_dst, ei, edge_attr, cnt, ellp,
        (unsigned short*)h, a_src, a_dst);

    gather_node<<<N_NODES / 4, 256, 0, stream>>>(
        cnt, ellp, a_src, a_dst, h, x, b, gamma, beta,
        att_edge, lin_w, lin_b, (float*)d_out);
}